// Round 1
// baseline (620.054 us; speedup 1.0000x reference)
//
#include <hip/hip_runtime.h>
#include <hip/hip_bf16.h>

typedef unsigned short u16;
typedef unsigned int u32;
typedef unsigned long long u64;
typedef __attribute__((ext_vector_type(8))) short short8;
typedef __attribute__((ext_vector_type(4))) float floatx4;

#if __has_builtin(__builtin_amdgcn_exp2f)
#define EXP2F(x) __builtin_amdgcn_exp2f(x)
#else
#define EXP2F(x) exp2f(x)
#endif

// SCALE * log2(e): softmax runs in base 2, scale pre-folded into Q cast.
#define QSCALE (0.07216878364870323f * 1.4426950408889634f)
#define ROPE_C 0.62286151779f   /* log2(1e6)/32 */

__device__ __forceinline__ u16 f2b(float f) {
    unsigned int x = __builtin_bit_cast(unsigned int, f);
    unsigned int r = (x + 0x7fffu + ((x >> 16) & 1u)) >> 16;   // RNE
    return (u16)r;
}
__device__ __forceinline__ u32 pk2(float a, float b) {
    return (u32)f2b(a) | ((u32)f2b(b) << 16);   // low 16 = a, high 16 = b
}
__device__ __forceinline__ void async16(const void* g, void* l) {
    __builtin_amdgcn_global_load_lds(
        (const __attribute__((address_space(1))) void*)g,
        (__attribute__((address_space(3))) void*)l, 16, 0, 0);
}

// ---------------------------------------------------------------- fused cast
struct CastArgs {
    const float* src[8];
    u16* dst[8];
    float scale[8];
    int startblk[8];
};

__global__ void cast_all_k(CastArgs a)
{
    const int bid = blockIdx.x;
    int s = 0;
#pragma unroll
    for (int i = 1; i < 8; ++i) s += (bid >= a.startblk[i]);
    const long idx = ((long)(bid - a.startblk[s]) * 256 + threadIdx.x) * 4;
    const float4 v = *(const float4*)(a.src[s] + idx);
    const float sc = a.scale[s];
    const u64 pk = (u64)pk2(v.x * sc, v.y * sc)
                 | ((u64)pk2(v.z * sc, v.w * sc) << 32);
    *(u64*)(a.dst[s] + idx) = pk;
}

// ---------------------------------------------------------------- GEMM  C = A(MxK) * B(NxK)^T
// 256x128 tile, BK=64, 512 threads = 8 waves (4M x 2N), 64x64 per wave.
// 3-slot LDS ring + counted vmcnt(6): while computing tile kt, issue tile kt+2
// into the slot vacated by kt-1. Loads keep a full tile of slack; vmcnt never
// drains to 0 in the main loop (T3+T4). Raw s_barrier (no __syncthreads drain).
// EPI 0 (Q merged, N=3072): col<2048 -> QC bf16 (ld 2048); col>=2048 -> RoPE -> QR (ld 1024)
// EPI 1 (KV merged, N=5120): col<2048 -> KC; 2048..3071 -> RoPE -> KR; >=3072 -> V transposed (b,hd,n)
// EPI 2 (final, N=2048): f32 row-major
template<int KK>
__device__ __forceinline__ void gemm_phase(const u16* asb, const u16* bsb,
                                           int wm, int wn, int lq, int lr,
                                           floatx4 (&acc)[4][4])
{
    short8 af[4], bf[4];
#pragma unroll
    for (int i = 0; i < 4; ++i) {
        const int row = wm + 16 * i + lr;
        const int cc = (KK * 4 + lq) ^ (row & 7);
        af[i] = *(const short8*)(asb + row * 64 + cc * 8);
    }
#pragma unroll
    for (int j = 0; j < 4; ++j) {
        const int row = wn + 16 * j + lr;
        const int cc = (KK * 4 + lq) ^ (row & 7);
        bf[j] = *(const short8*)(bsb + row * 64 + cc * 8);
    }
    __builtin_amdgcn_s_setprio(1);
#pragma unroll
    for (int i = 0; i < 4; ++i)
#pragma unroll
        for (int j = 0; j < 4; ++j)
            acc[i][j] = __builtin_amdgcn_mfma_f32_16x16x32_bf16(
                af[i], bf[j], acc[i][j], 0, 0, 0);
    __builtin_amdgcn_s_setprio(0);
}

template<int EPI>
__global__ void __launch_bounds__(512, 2)
gemm_bt(const u16* __restrict__ A, const u16* __restrict__ Bw,
        void* __restrict__ out0, u16* __restrict__ out1, u16* __restrict__ out2,
        int K)
{
    __shared__ u16 As[3][256 * 64];   // 96 KiB
    __shared__ u16 Bs[3][128 * 64];   // 48 KiB
    const int t = threadIdx.x;        // 0..511
    const int w = t >> 6;             // 0..7
    const int lane = t & 63;
    const int lq = lane >> 4, lr = lane & 15;

    // bijective XCD swizzle (all grids are multiples of 8); nbm = 16 always
    const int nwg = gridDim.x;
    const int id = blockIdx.x;
    const int wid = (id & 7) * (nwg >> 3) + (id >> 3);
    const long tileM = (long)(wid & 15) << 8;
    const long tileN = (long)(wid >> 4) << 7;

    const int wm = (w >> 1) * 64;     // 0,64,128,192
    const int wn = (w & 1) * 64;      // 0,64

    // per-thread staging descriptors (source pre-swizzled so LDS dest is linear)
    const u16* pA[4]; int dA[4];
    const u16* pB[2]; int dB[2];
#pragma unroll
    for (int r = 0; r < 4; ++r) {
        const int c = r * 512 + t;
        const int row = c >> 3, cc = c & 7;
        pA[r] = A + (tileM + row) * (long)K + ((cc ^ (row & 7)) << 3);
        dA[r] = c * 16;   // byte offset within one A slot (32 KiB)
    }
#pragma unroll
    for (int r = 0; r < 2; ++r) {
        const int c = r * 512 + t;
        const int row = c >> 3, cc = c & 7;
        pB[r] = Bw + (tileN + row) * (long)K + ((cc ^ (row & 7)) << 3);
        dB[r] = c * 16;   // byte offset within one B slot (16 KiB)
    }

    const floatx4 fzero = {0.f, 0.f, 0.f, 0.f};
    floatx4 acc[4][4];
#pragma unroll
    for (int i = 0; i < 4; ++i)
#pragma unroll
        for (int j = 0; j < 4; ++j) acc[i][j] = fzero;

    const int nt = K >> 6;            // 32

    // prologue: tile 0 -> slot 0, tile 1 -> slot 1 (order matches loop order)
    async16(pA[0], (char*)As + dA[0]);
    async16(pA[1], (char*)As + dA[1]);
    async16(pB[0], (char*)Bs + dB[0]);
    async16(pA[2], (char*)As + dA[2]);
    async16(pA[3], (char*)As + dA[3]);
    async16(pB[1], (char*)Bs + dB[1]);
    async16(pA[0] + 64, (char*)As + 32768 + dA[0]);
    async16(pA[1] + 64, (char*)As + 32768 + dA[1]);
    async16(pB[0] + 64, (char*)Bs + 16384 + dB[0]);
    async16(pA[2] + 64, (char*)As + 32768 + dA[2]);
    async16(pA[3] + 64, (char*)As + 32768 + dA[3]);
    async16(pB[1] + 64, (char*)Bs + 16384 + dB[1]);

    int slot = 0;
    for (int kt = 0; kt < nt; ++kt) {
        // tile kt must be resident; tile kt+1's 6 loads may stay in flight
        __builtin_amdgcn_sched_barrier(0);
        if (kt + 1 < nt) {
            asm volatile("s_waitcnt vmcnt(6)" ::: "memory");
        } else {
            asm volatile("s_waitcnt vmcnt(0)" ::: "memory");
        }
        __builtin_amdgcn_sched_barrier(0);
        __builtin_amdgcn_s_barrier();
        __builtin_amdgcn_sched_barrier(0);

        const u16* asb = &As[slot][0];
        const u16* bsb = &Bs[slot][0];
        const int s2 = (slot >= 1) ? slot - 1 : 2;        // (slot+2)%3
        const bool pf = (kt + 2 < nt);
        const long koff = (long)(kt + 2) << 6;

        // ---- phase 0 (kk=0): issue half of tile kt+2, read frags, 16 MFMA
        if (pf) {
            async16(pA[0] + koff, (char*)As + s2 * 32768 + dA[0]);
            async16(pA[1] + koff, (char*)As + s2 * 32768 + dA[1]);
            async16(pB[0] + koff, (char*)Bs + s2 * 16384 + dB[0]);
        }
        gemm_phase<0>(asb, bsb, wm, wn, lq, lr, acc);
        __builtin_amdgcn_sched_barrier(0);
        __builtin_amdgcn_s_barrier();
        __builtin_amdgcn_sched_barrier(0);

        // ---- phase 1 (kk=1): issue other half, read frags, 16 MFMA
        if (pf) {
            async16(pA[2] + koff, (char*)As + s2 * 32768 + dA[2]);
            async16(pA[3] + koff, (char*)As + s2 * 32768 + dA[3]);
            async16(pB[1] + koff, (char*)Bs + s2 * 16384 + dB[1]);
        }
        gemm_phase<1>(asb, bsb, wm, wn, lq, lr, acc);

        slot = (slot == 2) ? 0 : slot + 1;
    }

    // ---- epilogue (region is block-uniform: boundaries are multiples of 128)
    const bool isV    = (EPI == 1) && (tileN >= 3072);
    const bool isRope = (EPI != 2) && !isV && (tileN >= 2048);

#pragma unroll
    for (int i = 0; i < 4; ++i) {
#pragma unroll
        for (int j = 0; j < 4; ++j) {
            const long row0 = tileM + wm + 16 * i + 4 * lq;
            const long col  = tileN + wn + 16 * j + lr;
            if (EPI == 2) {
#pragma unroll
                for (int r = 0; r < 4; ++r)
                    ((float*)out0)[(row0 + r) * 2048 + col] = acc[i][j][r];
            } else if (isV) {
                const u32 lo = pk2(acc[i][j][0], acc[i][j][1]);
                const u32 hi = pk2(acc[i][j][2], acc[i][j][3]);
                const long bb = row0 >> 11;
                u16* dst = out2 + ((bb * 2048 + (col - 3072)) << 11) + (row0 & 2047);
                *(uint2*)dst = make_uint2(lo, hi);
            } else if (isRope) {
                const int jj = ((int)col & 63) >> 1;
                const float freq = EXP2F(-ROPE_C * (float)jj);
#pragma unroll
                for (int r = 0; r < 4; ++r) {
                    const float v = acc[i][j][r];
                    const float vp = __shfl_xor(v, 1, 64);
                    const long row = row0 + r;
                    float sn, cs;
                    __sincosf((float)(row & 2047) * freq, &sn, &cs);
                    const float o = (col & 1) ? (v * cs + vp * sn) : (v * cs - vp * sn);
                    out1[row * 1024 + (col - 2048)] = f2b(o);
                }
            } else {
#pragma unroll
                for (int r = 0; r < 4; ++r)
                    ((u16*)out0)[(row0 + r) * 2048 + col] = f2b(acc[i][j][r]);
            }
        }
    }
}

// ---------------------------------------------------------------- flash attention (S^T dataflow)
// grid (M/128, H, B), 256 threads (4 waves), wave owns a 32-row Q strip.
// Q pre-scaled by SCALE*log2e -> softmax in base 2.
// S^T = mfma(K-frag, Q-frag): m lands on lane&15 -> per-lane softmax rows.
// O^T = mfma(V-frag, P-frag): oacc cols = m -> scalar alpha rescale, direct 1/l.
__global__ void __launch_bounds__(256, 2)
flash_attn(const u16* __restrict__ QC, const u16* __restrict__ QR,
           const u16* __restrict__ KC, const u16* __restrict__ KR,
           const u16* __restrict__ VT, u16* __restrict__ Obuf)
{
    __shared__ u16 KC_s[64 * 128];
    __shared__ u16 KR_s[64 * 64];
    __shared__ u16 VT_s[128 * 64];
    __shared__ u16 P_s[4][32 * 72];   // per-wave P strip [m][n], stride 72 (2-way banks: free)

    const int t = threadIdx.x;
    const int w = t >> 6;
    const int lane = t & 63;
    const int lq = lane >> 4, lr = lane & 15;
    const int mbase = blockIdx.x * 128 + w * 32;
    const int h = blockIdx.y, b = blockIdx.z;

    // Q fragments (Y-operand layout [m=lane&15][k=lq*8+j]) in registers
    short8 aq[2][6];
#pragma unroll
    for (int i = 0; i < 2; ++i) {
        const long m = mbase + 16 * i + lr;
        const u16* qc = QC + ((long)b * 2048 + m) * 2048 + h * 128;
        const u16* qr = QR + ((long)b * 2048 + m) * 1024 + h * 64;
#pragma unroll
        for (int kc = 0; kc < 4; ++kc) aq[i][kc]     = *(const short8*)(qc + kc * 32 + lq * 8);
#pragma unroll
        for (int kc = 0; kc < 2; ++kc) aq[i][4 + kc] = *(const short8*)(qr + kc * 32 + lq * 8);
    }

    const floatx4 fzero = {0.f, 0.f, 0.f, 0.f};
    float mst[2], lst[2];
    floatx4 oacc[2][8];   // O^T: rows d (tile jn, 4lq+r), cols m = lr (strip i)
#pragma unroll
    for (int i = 0; i < 2; ++i) {
        mst[i] = -1e30f; lst[i] = 0.f;
#pragma unroll
        for (int jn = 0; jn < 8; ++jn) oacc[i][jn] = fzero;
    }

    const u16* kc_g = KC + ((long)b * 2048) * 2048 + h * 128;
    const u16* kr_g = KR + ((long)b * 2048) * 1024 + h * 64;
    const u16* vt_g = VT + ((long)(b * 16 + h) * 128) * 2048;

    for (int kt = 0; kt < 32; ++kt) {
#pragma unroll
        for (int r = 0; r < 4; ++r) {
            const int c = r * 256 + t;
            const int krow = c >> 4, cc = c & 15;
            const int gc = cc ^ (krow & 7);
            async16(kc_g + (long)(kt * 64 + krow) * 2048 + gc * 8, (char*)KC_s + c * 16);
        }
#pragma unroll
        for (int r = 0; r < 2; ++r) {
            const int c = r * 256 + t;
            const int krow = c >> 3, cc = c & 7;
            const int gc = cc ^ (krow & 7);
            async16(kr_g + (long)(kt * 64 + krow) * 1024 + gc * 8, (char*)KR_s + c * 16);
        }
#pragma unroll
        for (int r = 0; r < 4; ++r) {
            const int c = r * 256 + t;
            const int drow = c >> 3, cc = c & 7;
            const int gc = cc ^ (drow & 7);
            async16(vt_g + (long)drow * 2048 + kt * 64 + gc * 8, (char*)VT_s + c * 16);
        }
        __builtin_amdgcn_s_waitcnt(0);
        __syncthreads();

        // ---- S^T = K Q^T: sT[j][i] rows n (16j+4lq+r), cols m (16i, lane lr)
        floatx4 sT[4][2];
#pragma unroll
        for (int j = 0; j < 4; ++j)
#pragma unroll
            for (int i = 0; i < 2; ++i) sT[j][i] = fzero;
#pragma unroll
        for (int kc = 0; kc < 6; ++kc) {
            short8 kf[4];
#pragma unroll
            for (int j = 0; j < 4; ++j) {
                const int krow = 16 * j + lr;
                if (kc < 4) {
                    const int cc = (4 * kc + lq) ^ (krow & 7);
                    kf[j] = *(const short8*)(KC_s + krow * 128 + cc * 8);
                } else {
                    const int cc = (4 * (kc - 4) + lq) ^ (krow & 7);
                    kf[j] = *(const short8*)(KR_s + krow * 64 + cc * 8);
                }
            }
            __builtin_amdgcn_s_setprio(1);
#pragma unroll
            for (int j = 0; j < 4; ++j)
#pragma unroll
                for (int i = 0; i < 2; ++i)
                    sT[j][i] = __builtin_amdgcn_mfma_f32_16x16x32_bf16(
                        kf[j], aq[i][kc], sT[j][i], 0, 0, 0);
            __builtin_amdgcn_s_setprio(0);
        }

        // ---- online softmax: per-lane over 16 regs, then 2 shuffle rounds (lq groups)
        float rmax[2];
#pragma unroll
        for (int i = 0; i < 2; ++i) {
            float a0 = fmaxf(fmaxf(sT[0][i][0], sT[0][i][1]), fmaxf(sT[0][i][2], sT[0][i][3]));
            float a1 = fmaxf(fmaxf(sT[1][i][0], sT[1][i][1]), fmaxf(sT[1][i][2], sT[1][i][3]));
            float a2 = fmaxf(fmaxf(sT[2][i][0], sT[2][i][1]), fmaxf(sT[2][i][2], sT[2][i][3]));
            float a3 = fmaxf(fmaxf(sT[3][i][0], sT[3][i][1]), fmaxf(sT[3][i][2], sT[3][i][3]));
            rmax[i] = fmaxf(fmaxf(a0, a1), fmaxf(a2, a3));
        }
#pragma unroll
        for (int i = 0; i < 2; ++i) {
            rmax[i] = fmaxf(rmax[i], __shfl_xor(rmax[i], 16, 64));
            rmax[i] = fmaxf(rmax[i], __shfl_xor(rmax[i], 32, 64));
        }

        const int upd = (rmax[0] > mst[0]) | (rmax[1] > mst[1]);
        if (__any(upd)) {
#pragma unroll
            for (int i = 0; i < 2; ++i) {
                const float mnew = fmaxf(mst[i], rmax[i]);
                const float alpha = EXP2F(mst[i] - mnew);
                mst[i] = mnew;
                lst[i] *= alpha;
#pragma unroll
                for (int jn = 0; jn < 8; ++jn)
#pragma unroll
                    for (int r = 0; r < 4; ++r) oacc[i][jn][r] *= alpha;
            }
        }

        float rsum[2] = {0.f, 0.f};
#pragma unroll
        for (int j = 0; j < 4; ++j)
#pragma unroll
            for (int i = 0; i < 2; ++i)
#pragma unroll
                for (int r = 0; r < 4; ++r) {
                    const float p = EXP2F(sT[j][i][r] - mst[i]);
                    sT[j][i][r] = p;
                    rsum[i] += p;
                }
#pragma unroll
        for (int i = 0; i < 2; ++i) {
            rsum[i] += __shfl_xor(rsum[i], 16, 64);
            rsum[i] += __shfl_xor(rsum[i], 32, 64);
            lst[i] += rsum[i];
        }

        // ---- write P strip [m][n]: 4 consecutive n per lane -> b64 writes
        u16* pw = &P_s[w][0];
#pragma unroll
        for (int i = 0; i < 2; ++i)
#pragma unroll
            for (int j = 0; j < 4; ++j) {
                const u32 d0 = pk2(sT[j][i][0], sT[j][i][1]);
                const u32 d1 = pk2(sT[j][i][2], sT[j][i][3]);
                *(uint2*)(pw + (16 * i + lr) * 72 + 16 * j + 4 * lq) = make_uint2(d0, d1);
            }

        // ---- O^T += V^T P^T: mfma(V-frag, P-frag)
#pragma unroll
        for (int kc = 0; kc < 2; ++kc) {
            short8 ap[2];
#pragma unroll
            for (int i = 0; i < 2; ++i)
                ap[i] = *(const short8*)(&P_s[w][0] + (16 * i + lr) * 72 + kc * 32 + lq * 8);
            __builtin_amdgcn_s_setprio(1);
#pragma unroll
            for (int jn = 0; jn < 8; ++jn) {
                const int drow = 16 * jn + lr;
                const int cc = (4 * kc + lq) ^ (drow & 7);
                const short8 bv = *(const short8*)(VT_s + drow * 64 + cc * 8);
#pragma unroll
                for (int i = 0; i < 2; ++i)
                    oacc[i][jn] = __builtin_amdgcn_mfma_f32_16x16x32_bf16(
                        bv, ap[i], oacc[i][jn], 0, 0, 0);
            }
            __builtin_amdgcn_s_setprio(0);
        }
        __syncthreads();
    }

    // ---- epilogue: O^T / l -> bf16, 8B packed stores (4 consecutive d)
#pragma unroll
    for (int i = 0; i < 2; ++i) {
        const float rl = 1.0f / lst[i];
        const long row = (long)b * 2048 + mbase + 16 * i + lr;
#pragma unroll
        for (int jn = 0; jn < 8; ++jn) {
            const u32 lo = pk2(oacc[i][jn][0] * rl, oacc[i][jn][1] * rl);
            const u32 hi = pk2(oacc[i][jn][2] * rl, oacc[i][jn][3] * rl);
            u16* dst = Obuf + row * 2048 + h * 128 + 16 * jn + 4 * lq;
            *(uint2*)dst = make_uint2(lo, hi);
        }
    }
}

// ---------------------------------------------------------------- launch
extern "C" void kernel_launch(void* const* d_in, const int* in_sizes, int n_in,
                              void* d_out, int out_size, void* d_ws, size_t ws_size,
                              hipStream_t stream)
{
    (void)in_sizes; (void)n_in; (void)out_size; (void)ws_size;

    u16* p = (u16*)d_ws;
    u16* qbf   = p; p += 8388608;
    u16* kvbf  = p; p += 8388608;
    u16* wqall = p; p += 6291456;   // rows 0..2047 = W_QC, 2048..3071 = W_QR
    u16* wkvall= p; p += 10485760;  // rows 0..2047 = W_KC, 2048..3071 = W_KR, 3072..5119 = W_V
    u16* wob   = p; p += 4194304;
    u16* QCb   = p; p += 8388608;
    u16* QRb   = p; p += 4194304;
    u16* KCb   = p; p += 8388608;
    u16* KRb   = p; p += 4194304;
    u16* VTb   = p; p += 8388608;
    u16* Ob    = p; p += 8388608;

    CastArgs a;
    a.src[0] = (const float*)d_in[0]; a.dst[0] = qbf;               a.scale[0] = QSCALE;
    a.src[1] = (const float*)d_in[1]; a.dst[1] = kvbf;              a.scale[1] = 1.f;
    a.src[2] = (const float*)d_in[2]; a.dst[2] = wqall;             a.scale[2] = 1.f;
    a.src[3] = (const float*)d_in[3]; a.dst[3] = wkvall;            a.scale[3] = 1.f;
    a.src[4] = (const float*)d_in[4]; a.dst[4] = wqall + 4194304;   a.scale[4] = 1.f;
    a.src[5] = (const float*)d_in[5]; a.dst[5] = wkvall + 4194304;  a.scale[5] = 1.f;
    a.src[6] = (const float*)d_in[6]; a.dst[6] = wkvall + 6291456;  a.scale[6] = 1.f;
    a.src[7] = (const float*)d_in[7]; a.dst[7] = wob;               a.scale[7] = 1.f;
    const int blks[8] = {8192, 8192, 4096, 4096, 2048, 2048, 4096, 4096};
    int acc = 0;
    for (int i = 0; i < 8; ++i) { a.startblk[i] = acc; acc += blks[i]; }

    cast_all_k<<<acc, 256, 0, stream>>>(a);

    // 1D grids: nbm=16 m-blocks (hardcoded in kernel), nbn = N/128
    gemm_bt<0><<<16 * 24, 512, 0, stream>>>(qbf,  wqall,  QCb, QRb, nullptr, 2048);
    gemm_bt<1><<<16 * 40, 512, 0, stream>>>(kvbf, wkvall, KCb, KRb, VTb,     2048);

    flash_attn<<<dim3(16, 16, 2), 256, 0, stream>>>(QCb, QRb, KCb, KRb, VTb, Ob);

    gemm_bt<2><<<16 * 16, 512, 0, stream>>>(Ob, wob, d_out, nullptr, nullptr, 2048);
}

// Round 4
// 484.332 us; speedup vs baseline: 1.2802x; 1.2802x over previous
//
#include <hip/hip_runtime.h>
#include <hip/hip_bf16.h>

typedef unsigned short u16;
typedef unsigned int u32;
typedef unsigned long long u64;
typedef __attribute__((ext_vector_type(8))) short short8;
typedef __attribute__((ext_vector_type(4))) float floatx4;

#if __has_builtin(__builtin_amdgcn_exp2f)
#define EXP2F(x) __builtin_amdgcn_exp2f(x)
#else
#define EXP2F(x) exp2f(x)
#endif

// SCALE * log2(e): softmax runs in base 2, scale pre-folded into Q cast.
#define QSCALE (0.07216878364870323f * 1.4426950408889634f)
#define ROPE_C 0.62286151779f   /* log2(1e6)/32 */

__device__ __forceinline__ u16 f2b(float f) {
    unsigned int x = __builtin_bit_cast(unsigned int, f);
    unsigned int r = (x + 0x7fffu + ((x >> 16) & 1u)) >> 16;   // RNE
    return (u16)r;
}
__device__ __forceinline__ u32 pk2(float a, float b) {
    return (u32)f2b(a) | ((u32)f2b(b) << 16);   // low 16 = a, high 16 = b
}
__device__ __forceinline__ void async16(const void* g, void* l) {
    __builtin_amdgcn_global_load_lds(
        (const __attribute__((address_space(1))) void*)g,
        (__attribute__((address_space(3))) void*)l, 16, 0, 0);
}

// ---------------------------------------------------------------- fused cast
struct CastArgs {
    const float* src[8];
    u16* dst[8];
    float scale[8];
    int startblk[8];
};

__global__ void cast_all_k(CastArgs a)
{
    const int bid = blockIdx.x;
    int s = 0;
#pragma unroll
    for (int i = 1; i < 8; ++i) s += (bid >= a.startblk[i]);
    const long idx = ((long)(bid - a.startblk[s]) * 256 + threadIdx.x) * 4;
    const float4 v = *(const float4*)(a.src[s] + idx);
    const float sc = a.scale[s];
    const u64 pk = (u64)pk2(v.x * sc, v.y * sc)
                 | ((u64)pk2(v.z * sc, v.w * sc) << 32);
    *(u64*)(a.dst[s] + idx) = pk;
}

// ---------------------------------------------------------------- GEMM  C = A(MxK) * B(NxK)^T
// Proven 128x128 / 256-thread / 3-blocks-per-CU structure (round-0 baseline),
// plus T1 bijective XCD swizzle: 1D grid, id -> wid = (id%8)*(nwg/8)+id/8,
// m-fastest within each XCD chunk so B-panels are reused inside one L2.
// EPI 0 (Q merged, N=3072): col<2048 -> QC bf16 (ld 2048); col>=2048 -> RoPE -> QR (ld 1024)
// EPI 1 (KV merged, N=5120): col<2048 -> KC; 2048..3071 -> RoPE -> KR; >=3072 -> V transposed (b,hd,n)
// EPI 2 (final, N=2048): f32 row-major
template<int EPI>
__global__ void __launch_bounds__(256, 3)
gemm_bt(const u16* __restrict__ A, const u16* __restrict__ Bw,
        void* __restrict__ out0, u16* __restrict__ out1, u16* __restrict__ out2,
        int K)
{
    __shared__ u16 As[128 * 64];
    __shared__ u16 Bs[128 * 64];
    const int t = threadIdx.x;
    const int w = t >> 6;
    const int lane = t & 63;
    const int lq = lane >> 4, lr = lane & 15;

    // bijective XCD swizzle (all grids are multiples of 8); nbm = 32 (M=4096)
    const int nwg = gridDim.x;
    const int id = blockIdx.x;
    const int wid = (id & 7) * (nwg >> 3) + (id >> 3);
    const long tileM = (long)(wid & 31) << 7;
    const long tileN = (long)(wid >> 5) << 7;

    const int wm = (w >> 1) * 64, wn = (w & 1) * 64;

    const floatx4 fzero = {0.f, 0.f, 0.f, 0.f};
    floatx4 acc[4][4];
#pragma unroll
    for (int i = 0; i < 4; ++i)
#pragma unroll
        for (int j = 0; j < 4; ++j) acc[i][j] = fzero;

    for (int k0 = 0; k0 < K; k0 += 64) {
#pragma unroll
        for (int r = 0; r < 4; ++r) {
            const int c = r * 256 + t;
            const int row = c >> 3, cc = c & 7;
            const int gcol = ((cc ^ (row & 7)) << 3);
            async16(A + (tileM + row) * (long)K + k0 + gcol, (char*)As + c * 16);
        }
#pragma unroll
        for (int r = 0; r < 4; ++r) {
            const int c = r * 256 + t;
            const int row = c >> 3, cc = c & 7;
            const int gcol = ((cc ^ (row & 7)) << 3);
            async16(Bw + (tileN + row) * (long)K + k0 + gcol, (char*)Bs + c * 16);
        }
        __builtin_amdgcn_s_waitcnt(0);
        __syncthreads();
#pragma unroll
        for (int kk = 0; kk < 2; ++kk) {
            short8 af[4], bfr[4];
#pragma unroll
            for (int i = 0; i < 4; ++i) {
                const int row = wm + 16 * i + lr;
                const int cc = (kk * 4 + lq) ^ (row & 7);
                af[i] = *(const short8*)(As + row * 64 + cc * 8);
            }
#pragma unroll
            for (int j = 0; j < 4; ++j) {
                const int row = wn + 16 * j + lr;
                const int cc = (kk * 4 + lq) ^ (row & 7);
                bfr[j] = *(const short8*)(Bs + row * 64 + cc * 8);
            }
            __builtin_amdgcn_s_setprio(1);
#pragma unroll
            for (int i = 0; i < 4; ++i)
#pragma unroll
                for (int j = 0; j < 4; ++j)
                    acc[i][j] = __builtin_amdgcn_mfma_f32_16x16x32_bf16(
                        af[i], bfr[j], acc[i][j], 0, 0, 0);
            __builtin_amdgcn_s_setprio(0);
        }
        __syncthreads();
    }

    // ---- epilogue (region is block-uniform: boundaries are multiples of 128)
    const bool isV    = (EPI == 1) && (tileN >= 3072);
    const bool isRope = (EPI != 2) && !isV && (tileN >= 2048);

#pragma unroll
    for (int i = 0; i < 4; ++i) {
#pragma unroll
        for (int j = 0; j < 4; ++j) {
            const long row0 = tileM + wm + 16 * i + 4 * lq;
            const long col  = tileN + wn + 16 * j + lr;
            if (EPI == 2) {
#pragma unroll
                for (int r = 0; r < 4; ++r)
                    ((float*)out0)[(row0 + r) * 2048 + col] = acc[i][j][r];
            } else if (isV) {
                const u32 lo = pk2(acc[i][j][0], acc[i][j][1]);
                const u32 hi = pk2(acc[i][j][2], acc[i][j][3]);
                const long bb = row0 >> 11;
                u16* dst = out2 + ((bb * 2048 + (col - 3072)) << 11) + (row0 & 2047);
                *(uint2*)dst = make_uint2(lo, hi);
            } else if (isRope) {
                const int jj = ((int)col & 63) >> 1;
                const float freq = EXP2F(-ROPE_C * (float)jj);
#pragma unroll
                for (int r = 0; r < 4; ++r) {
                    const float v = acc[i][j][r];
                    const float vp = __shfl_xor(v, 1, 64);
                    const long row = row0 + r;
                    float sn, cs;
                    __sincosf((float)(row & 2047) * freq, &sn, &cs);
                    const float o = (col & 1) ? (v * cs + vp * sn) : (v * cs - vp * sn);
                    out1[row * 1024 + (col - 2048)] = f2b(o);
                }
            } else {
#pragma unroll
                for (int r = 0; r < 4; ++r)
                    ((u16*)out0)[(row0 + r) * 2048 + col] = f2b(acc[i][j][r]);
            }
        }
    }
}

// ---------------------------------------------------------------- flash attention (S^T dataflow)
// grid (16, 16, 2), 256 threads (4 waves), wave owns a 32-row Q strip.
// XCD remap: h = 2*(x&7) + (y&1), qx = 8*(x>>3) + (y>>1) (bijective).
// All 16 Q-tiles of a head land on one XCD -> its K/V panels (1.25 MB) stay in
// that XCD's L2 (2 heads x 1.25 MB < 4 MiB) instead of being fetched by 8 L2s.
__global__ void __launch_bounds__(256, 2)
flash_attn(const u16* __restrict__ QC, const u16* __restrict__ QR,
           const u16* __restrict__ KC, const u16* __restrict__ KR,
           const u16* __restrict__ VT, u16* __restrict__ Obuf)
{
    __shared__ u16 KC_s[64 * 128];
    __shared__ u16 KR_s[64 * 64];
    __shared__ u16 VT_s[128 * 64];
    __shared__ u16 P_s[4][32 * 72];   // per-wave P strip [m][n], stride 72 (2-way banks: free)

    const int t = threadIdx.x;
    const int w = t >> 6;
    const int lane = t & 63;
    const int lq = lane >> 4, lr = lane & 15;
    const int bx = blockIdx.x, by = blockIdx.y;
    const int h  = ((bx & 7) << 1) | (by & 1);     // head: fixed x&7 -> fixed XCD
    const int qx = ((bx >> 3) << 3) | (by >> 1);   // Q tile index 0..15
    const int mbase = qx * 128 + w * 32;
    const int b = blockIdx.z;

    // Q fragments (Y-operand layout [m=lane&15][k=lq*8+j]) in registers
    short8 aq[2][6];
#pragma unroll
    for (int i = 0; i < 2; ++i) {
        const long m = mbase + 16 * i + lr;
        const u16* qc = QC + ((long)b * 2048 + m) * 2048 + h * 128;
        const u16* qr = QR + ((long)b * 2048 + m) * 1024 + h * 64;
#pragma unroll
        for (int kc = 0; kc < 4; ++kc) aq[i][kc]     = *(const short8*)(qc + kc * 32 + lq * 8);
#pragma unroll
        for (int kc = 0; kc < 2; ++kc) aq[i][4 + kc] = *(const short8*)(qr + kc * 32 + lq * 8);
    }

    const floatx4 fzero = {0.f, 0.f, 0.f, 0.f};
    float mst[2], lst[2];
    floatx4 oacc[2][8];   // O^T: rows d (tile jn, 4lq+r), cols m = lr (strip i)
#pragma unroll
    for (int i = 0; i < 2; ++i) {
        mst[i] = -1e30f; lst[i] = 0.f;
#pragma unroll
        for (int jn = 0; jn < 8; ++jn) oacc[i][jn] = fzero;
    }

    const u16* kc_g = KC + ((long)b * 2048) * 2048 + h * 128;
    const u16* kr_g = KR + ((long)b * 2048) * 1024 + h * 64;
    const u16* vt_g = VT + ((long)(b * 16 + h) * 128) * 2048;

    for (int kt = 0; kt < 32; ++kt) {
#pragma unroll
        for (int r = 0; r < 4; ++r) {
            const int c = r * 256 + t;
            const int krow = c >> 4, cc = c & 15;
            const int gc = cc ^ (krow & 7);
            async16(kc_g + (long)(kt * 64 + krow) * 2048 + gc * 8, (char*)KC_s + c * 16);
        }
#pragma unroll
        for (int r = 0; r < 2; ++r) {
            const int c = r * 256 + t;
            const int krow = c >> 3, cc = c & 7;
            const int gc = cc ^ (krow & 7);
            async16(kr_g + (long)(kt * 64 + krow) * 1024 + gc * 8, (char*)KR_s + c * 16);
        }
#pragma unroll
        for (int r = 0; r < 4; ++r) {
            const int c = r * 256 + t;
            const int drow = c >> 3, cc = c & 7;
            const int gc = cc ^ (drow & 7);
            async16(vt_g + (long)drow * 2048 + kt * 64 + gc * 8, (char*)VT_s + c * 16);
        }
        __builtin_amdgcn_s_waitcnt(0);
        __syncthreads();

        // ---- S^T = K Q^T: sT[j][i] rows n (16j+4lq+r), cols m (16i, lane lr)
        floatx4 sT[4][2];
#pragma unroll
        for (int j = 0; j < 4; ++j)
#pragma unroll
            for (int i = 0; i < 2; ++i) sT[j][i] = fzero;
#pragma unroll
        for (int kc = 0; kc < 6; ++kc) {
            short8 kf[4];
#pragma unroll
            for (int j = 0; j < 4; ++j) {
                const int krow = 16 * j + lr;
                if (kc < 4) {
                    const int cc = (4 * kc + lq) ^ (krow & 7);
                    kf[j] = *(const short8*)(KC_s + krow * 128 + cc * 8);
                } else {
                    const int cc = (4 * (kc - 4) + lq) ^ (krow & 7);
                    kf[j] = *(const short8*)(KR_s + krow * 64 + cc * 8);
                }
            }
            __builtin_amdgcn_s_setprio(1);
#pragma unroll
            for (int j = 0; j < 4; ++j)
#pragma unroll
                for (int i = 0; i < 2; ++i)
                    sT[j][i] = __builtin_amdgcn_mfma_f32_16x16x32_bf16(
                        kf[j], aq[i][kc], sT[j][i], 0, 0, 0);
            __builtin_amdgcn_s_setprio(0);
        }

        // ---- online softmax: per-lane over 16 regs, then 2 shuffle rounds (lq groups)
        float rmax[2];
#pragma unroll
        for (int i = 0; i < 2; ++i) {
            float a0 = fmaxf(fmaxf(sT[0][i][0], sT[0][i][1]), fmaxf(sT[0][i][2], sT[0][i][3]));
            float a1 = fmaxf(fmaxf(sT[1][i][0], sT[1][i][1]), fmaxf(sT[1][i][2], sT[1][i][3]));
            float a2 = fmaxf(fmaxf(sT[2][i][0], sT[2][i][1]), fmaxf(sT[2][i][2], sT[2][i][3]));
            float a3 = fmaxf(fmaxf(sT[3][i][0], sT[3][i][1]), fmaxf(sT[3][i][2], sT[3][i][3]));
            rmax[i] = fmaxf(fmaxf(a0, a1), fmaxf(a2, a3));
        }
#pragma unroll
        for (int i = 0; i < 2; ++i) {
            rmax[i] = fmaxf(rmax[i], __shfl_xor(rmax[i], 16, 64));
            rmax[i] = fmaxf(rmax[i], __shfl_xor(rmax[i], 32, 64));
        }

        const int upd = (rmax[0] > mst[0]) | (rmax[1] > mst[1]);
        if (__any(upd)) {
#pragma unroll
            for (int i = 0; i < 2; ++i) {
                const float mnew = fmaxf(mst[i], rmax[i]);
                const float alpha = EXP2F(mst[i] - mnew);
                mst[i] = mnew;
                lst[i] *= alpha;
#pragma unroll
                for (int jn = 0; jn < 8; ++jn)
#pragma unroll
                    for (int r = 0; r < 4; ++r) oacc[i][jn][r] *= alpha;
            }
        }

        float rsum[2] = {0.f, 0.f};
#pragma unroll
        for (int j = 0; j < 4; ++j)
#pragma unroll
            for (int i = 0; i < 2; ++i)
#pragma unroll
                for (int r = 0; r < 4; ++r) {
                    const float p = EXP2F(sT[j][i][r] - mst[i]);
                    sT[j][i][r] = p;
                    rsum[i] += p;
                }
#pragma unroll
        for (int i = 0; i < 2; ++i) {
            rsum[i] += __shfl_xor(rsum[i], 16, 64);
            rsum[i] += __shfl_xor(rsum[i], 32, 64);
            lst[i] += rsum[i];
        }

        // ---- write P strip [m][n]: 4 consecutive n per lane -> b64 writes
        u16* pw = &P_s[w][0];
#pragma unroll
        for (int i = 0; i < 2; ++i)
#pragma unroll
            for (int j = 0; j < 4; ++j) {
                const u32 d0 = pk2(sT[j][i][0], sT[j][i][1]);
                const u32 d1 = pk2(sT[j][i][2], sT[j][i][3]);
                *(uint2*)(pw + (16 * i + lr) * 72 + 16 * j + 4 * lq) = make_uint2(d0, d1);
            }

        // ---- O^T += V^T P^T: mfma(V-frag, P-frag)
#pragma unroll
        for (int kc = 0; kc < 2; ++kc) {
            short8 ap[2];
#pragma unroll
            for (int i = 0; i < 2; ++i)
                ap[i] = *(const short8*)(&P_s[w][0] + (16 * i + lr) * 72 + kc * 32 + lq * 8);
            __builtin_amdgcn_s_setprio(1);
#pragma unroll
            for (int jn = 0; jn < 8; ++jn) {
                const int drow = 16 * jn + lr;
                const int cc = (4 * kc + lq) ^ (drow & 7);
                const short8 bv = *(const short8*)(VT_s + drow * 64 + cc * 8);
#pragma unroll
                for (int i = 0; i < 2; ++i)
                    oacc[i][jn] = __builtin_amdgcn_mfma_f32_16x16x32_bf16(
                        bv, ap[i], oacc[i][jn], 0, 0, 0);
            }
            __builtin_amdgcn_s_setprio(0);
        }
        __syncthreads();
    }

    // ---- epilogue: O^T / l -> bf16, 8B packed stores (4 consecutive d)
#pragma unroll
    for (int i = 0; i < 2; ++i) {
        const float rl = 1.0f / lst[i];
        const long row = (long)b * 2048 + mbase + 16 * i + lr;
#pragma unroll
        for (int jn = 0; jn < 8; ++jn) {
            const u32 lo = pk2(oacc[i][jn][0] * rl, oacc[i][jn][1] * rl);
            const u32 hi = pk2(oacc[i][jn][2] * rl, oacc[i][jn][3] * rl);
            u16* dst = Obuf + row * 2048 + h * 128 + 16 * jn + 4 * lq;
            *(uint2*)dst = make_uint2(lo, hi);
        }
    }
}

// ---------------------------------------------------------------- launch
extern "C" void kernel_launch(void* const* d_in, const int* in_sizes, int n_in,
                              void* d_out, int out_size, void* d_ws, size_t ws_size,
                              hipStream_t stream)
{
    (void)in_sizes; (void)n_in; (void)out_size; (void)ws_size;

    u16* p = (u16*)d_ws;
    u16* qbf   = p; p += 8388608;
    u16* kvbf  = p; p += 8388608;
    u16* wqall = p; p += 6291456;   // rows 0..2047 = W_QC, 2048..3071 = W_QR
    u16* wkvall= p; p += 10485760;  // rows 0..2047 = W_KC, 2048..3071 = W_KR, 3072..5119 = W_V
    u16* wob   = p; p += 4194304;
    u16* QCb   = p; p += 8388608;
    u16* QRb   = p; p += 4194304;
    u16* KCb   = p; p += 8388608;
    u16* KRb   = p; p += 4194304;
    u16* VTb   = p; p += 8388608;
    u16* Ob    = p; p += 8388608;

    CastArgs a;
    a.src[0] = (const float*)d_in[0]; a.dst[0] = qbf;               a.scale[0] = QSCALE;
    a.src[1] = (const float*)d_in[1]; a.dst[1] = kvbf;              a.scale[1] = 1.f;
    a.src[2] = (const float*)d_in[2]; a.dst[2] = wqall;             a.scale[2] = 1.f;
    a.src[3] = (const float*)d_in[3]; a.dst[3] = wkvall;            a.scale[3] = 1.f;
    a.src[4] = (const float*)d_in[4]; a.dst[4] = wqall + 4194304;   a.scale[4] = 1.f;
    a.src[5] = (const float*)d_in[5]; a.dst[5] = wkvall + 4194304;  a.scale[5] = 1.f;
    a.src[6] = (const float*)d_in[6]; a.dst[6] = wkvall + 6291456;  a.scale[6] = 1.f;
    a.src[7] = (const float*)d_in[7]; a.dst[7] = wob;               a.scale[7] = 1.f;
    const int blks[8] = {8192, 8192, 4096, 4096, 2048, 2048, 4096, 4096};
    int acc = 0;
    for (int i = 0; i < 8; ++i) { a.startblk[i] = acc; acc += blks[i]; }

    cast_all_k<<<acc, 256, 0, stream>>>(a);

    // 1D grids (nbm=32 hardcoded in kernel): nwg = 32 * (N/128)
    gemm_bt<0><<<32 * 24, 256, 0, stream>>>(qbf,  wqall,  QCb, QRb, nullptr, 2048);
    gemm_bt<1><<<32 * 40, 256, 0, stream>>>(kvbf, wkvall, KCb, KRb, VTb,     2048);

    flash_attn<<<dim3(16, 16, 2), 256, 0, stream>>>(QCb, QRb, KCb, KRb, VTb, Ob);

    gemm_bt<2><<<32 * 16, 256, 0, stream>>>(Ob, wob, d_out, nullptr, nullptr, 2048);
}